// Round 1
// baseline (325.835 us; speedup 1.0000x reference)
//
#include <hip/hip_runtime.h>
#include <hip/hip_bf16.h>
#include <stdint.h>

// ---------- types ----------
typedef __attribute__((ext_vector_type(8))) short          bf16x8;
typedef __attribute__((ext_vector_type(4))) float          f32x4;
typedef __attribute__((ext_vector_type(4))) float          f4;
typedef __attribute__((ext_vector_type(8))) unsigned short u16x8;
typedef __attribute__((ext_vector_type(4))) unsigned short u16x4;

#define DEVINL __device__ __forceinline__

static constexpr int B  = 4;
static constexpr int S  = 4096;
static constexpr int D  = 256;
static constexpr int SP = 410;   // ceil(4096/10), SAME pooling, pad_lo = 2

DEVINL unsigned short f2bf(float x) {
  union { float f; unsigned u; } v; v.f = x;
  unsigned r = v.u + 0x7FFFu + ((v.u >> 16) & 1u);   // round-to-nearest-even
  return (unsigned short)(r >> 16);
}

DEVINL f32x4 mfma16(bf16x8 a, bf16x8 b, f32x4 c) {
  return __builtin_amdgcn_mfma_f32_16x16x32_bf16(a, b, c, 0, 0, 0);
}

// ---------- K0: transpose + convert the 4 weight matrices to bf16 [n][k] ----------
__global__ __launch_bounds__(256) void wt_trans_kernel(
    const float* __restrict__ wq, const float* __restrict__ wk,
    const float* __restrict__ wv, const float* __restrict__ wo,
    unsigned short* __restrict__ wt)
{
  int idx = blockIdx.x * 256 + threadIdx.x;   // 4 * 256 * 256
  int mat = idx >> 16;
  int r   = idx & 65535;
  int n   = r >> 8;
  int k   = r & 255;
  const float* w = (mat == 0) ? wq : (mat == 1) ? wk : (mat == 2) ? wv : wo;
  wt[idx] = f2bf(w[k * 256 + n]);             // wt[mat][n][k] = w[k][n]
}

// ---------- K1: fused QKV projections (bf16 MFMA, fp32 A converted in staging) ----------
// C[m][n] = sum_k A_f32[m][k] * WT_bf16[n][k] + bias[n]  -> bf16 out
__global__ __launch_bounds__(256) void proj_kernel(
    const float* __restrict__ xq, const float* __restrict__ xk, const float* __restrict__ xv,
    const unsigned short* __restrict__ wt,
    const float* __restrict__ bq, const float* __restrict__ bk, const float* __restrict__ bv,
    unsigned short* __restrict__ qp, unsigned short* __restrict__ kp, unsigned short* __restrict__ vp)
{
  int z = blockIdx.z;
  const float* A            = (z == 0) ? xq : (z == 1) ? xk : xv;
  const unsigned short* W   = wt + z * 65536;
  const float* bias         = (z == 0) ? bq : (z == 1) ? bk : bv;
  unsigned short* Out       = (z == 0) ? qp : (z == 1) ? kp : vp;

  int m0 = blockIdx.x * 128;        // over B*S = 16384
  int n0 = blockIdx.y * 128;        // over 256

  __shared__ unsigned short As[128][40];
  __shared__ unsigned short Bs[128][40];

  int tid  = threadIdx.x;
  int lane = tid & 63, wid = tid >> 6;
  int wr = wid >> 1, wc = wid & 1;        // 2x2 waves, 64x64 each
  int lrow = lane & 15, kseg = lane >> 4;

  f32x4 zero4 = {0.f, 0.f, 0.f, 0.f};
  f32x4 acc[4][4];
#pragma unroll
  for (int i = 0; i < 4; i++)
#pragma unroll
    for (int j = 0; j < 4; j++) acc[i][j] = zero4;

  for (int ks = 0; ks < 256; ks += 32) {
    // stage A (fp32 -> bf16): 128 rows x 32 cols; 1024 slots of float4
    for (int s = tid; s < 1024; s += 256) {
      int row = s >> 3, seg = s & 7;
      f4 v = *reinterpret_cast<const f4*>(&A[(size_t)(m0 + row) * 256 + ks + seg * 4]);
      u16x4 h;
      h[0] = f2bf(v[0]); h[1] = f2bf(v[1]); h[2] = f2bf(v[2]); h[3] = f2bf(v[3]);
      *reinterpret_cast<u16x4*>(&As[row][seg * 4]) = h;
    }
    // stage B (bf16): 128 rows(n) x 32(k); 512 slots of 16B
    for (int s = tid; s < 512; s += 256) {
      int row = s >> 2, seg = s & 3;
      u16x8 v = *reinterpret_cast<const u16x8*>(&W[(size_t)(n0 + row) * 256 + ks + seg * 8]);
      *reinterpret_cast<u16x8*>(&Bs[row][seg * 8]) = v;
    }
    __syncthreads();
    bf16x8 af[4], bfr[4];
#pragma unroll
    for (int rf = 0; rf < 4; rf++)
      af[rf] = *reinterpret_cast<const bf16x8*>(&As[wr * 64 + rf * 16 + lrow][kseg * 8]);
#pragma unroll
    for (int cf = 0; cf < 4; cf++)
      bfr[cf] = *reinterpret_cast<const bf16x8*>(&Bs[wc * 64 + cf * 16 + lrow][kseg * 8]);
#pragma unroll
    for (int rf = 0; rf < 4; rf++)
#pragma unroll
      for (int cf = 0; cf < 4; cf++)
        acc[rf][cf] = mfma16(af[rf], bfr[cf], acc[rf][cf]);
    __syncthreads();
  }

  int r4 = (lane >> 4) * 4;
#pragma unroll
  for (int rf = 0; rf < 4; rf++)
#pragma unroll
    for (int cf = 0; cf < 4; cf++) {
      int n = n0 + wc * 64 + cf * 16 + lrow;
      float bv_ = bias[n];
#pragma unroll
      for (int r = 0; r < 4; r++) {
        int m = m0 + wr * 64 + rf * 16 + r4 + r;
        Out[(size_t)m * 256 + n] = f2bf(acc[rf][cf][r] + bv_);
      }
    }
}

// ---------- K2: scores GEMM + fused max-pool over q ----------
// pooled[b][w][n] = max_{q in [10w-2,10w+8) ∩ [0,S)} (qp[b][q] . kp[b][n]) / 16
__global__ __launch_bounds__(512) void scores_pool_kernel(
    const unsigned short* __restrict__ qp, const unsigned short* __restrict__ kp,
    float* __restrict__ pooled)
{
  int b  = blockIdx.z;
  int wb = blockIdx.y;              // 0..25 (16 windows each)
  int nb = blockIdx.x;              // 0..31 (128 cols each)
  int w0 = wb * 16;
  int qb = w0 * 10 - 2;             // first q row of this block (may be < 0)
  int n0 = nb * 128;

  union SM {
    struct { unsigned short A[160][40]; unsigned short Bs[128][40]; } st;
    float sc[160][65];
  };
  __shared__ SM sm;

  const unsigned short* qpb = qp + (size_t)b * S * 256;
  const unsigned short* kpb = kp + (size_t)b * S * 256;

  int tid  = threadIdx.x;
  int lane = tid & 63, wid = tid >> 6;   // 8 waves
  int wr = wid >> 2, wc = wid & 3;       // 2x4: wave = 80 rows x 32 cols
  int lrow = lane & 15, kseg = lane >> 4;

  f32x4 zero4 = {0.f, 0.f, 0.f, 0.f};
  f32x4 acc[5][2];
#pragma unroll
  for (int i = 0; i < 5; i++) { acc[i][0] = zero4; acc[i][1] = zero4; }

  for (int ks = 0; ks < 256; ks += 32) {
    for (int s = tid; s < 640; s += 512) {       // A: 160 rows x 4 segs
      int row = s >> 2, seg = s & 3;
      int q = qb + row; q = (q < 0) ? 0 : ((q > S - 1) ? (S - 1) : q);
      u16x8 v = *reinterpret_cast<const u16x8*>(&qpb[(size_t)q * 256 + ks + seg * 8]);
      *reinterpret_cast<u16x8*>(&sm.st.A[row][seg * 8]) = v;
    }
    {                                            // B: 128 rows x 4 segs (exactly 1 slot/thread)
      int s = tid;
      int row = s >> 2, seg = s & 3;
      u16x8 v = *reinterpret_cast<const u16x8*>(&kpb[(size_t)(n0 + row) * 256 + ks + seg * 8]);
      *reinterpret_cast<u16x8*>(&sm.st.Bs[row][seg * 8]) = v;
    }
    __syncthreads();
    bf16x8 af[5], bfr[2];
#pragma unroll
    for (int rf = 0; rf < 5; rf++)
      af[rf] = *reinterpret_cast<const bf16x8*>(&sm.st.A[wr * 80 + rf * 16 + lrow][kseg * 8]);
#pragma unroll
    for (int cf = 0; cf < 2; cf++)
      bfr[cf] = *reinterpret_cast<const bf16x8*>(&sm.st.Bs[wc * 32 + cf * 16 + lrow][kseg * 8]);
#pragma unroll
    for (int rf = 0; rf < 5; rf++)
#pragma unroll
      for (int cf = 0; cf < 2; cf++)
        acc[rf][cf] = mfma16(af[rf], bfr[cf], acc[rf][cf]);
    __syncthreads();
  }

  // pooling, two 64-col chunks through LDS
  int r4 = (lane >> 4) * 4;
#pragma unroll
  for (int c = 0; c < 2; c++) {
    if ((wc >> 1) == c) {
#pragma unroll
      for (int rf = 0; rf < 5; rf++)
#pragma unroll
        for (int cf = 0; cf < 2; cf++) {
          int coll = (wc & 1) * 32 + cf * 16 + lrow;
#pragma unroll
          for (int r = 0; r < 4; r++) {
            int rowl = wr * 80 + rf * 16 + r4 + r;
            sm.sc[rowl][coll] = acc[rf][cf][r];
          }
        }
    }
    __syncthreads();
    for (int s = tid; s < 1024; s += 512) {
      int wl = s >> 6, col = s & 63;
      int wg = w0 + wl;
      if (wg < SP) {
        float m = -3.4e38f;
#pragma unroll
        for (int j = 0; j < 10; j++) {
          int r = wl * 10 + j;
          int q = qb + r;
          if (q >= 0 && q < S) m = fmaxf(m, sm.sc[r][col]);
        }
        pooled[((size_t)b * SP + wg) * 4096 + n0 + c * 64 + col] = m * 0.0625f;
      }
    }
    __syncthreads();
  }
}

// ---------- K3: row softmax (4096 cols), fp32 in, bf16 out ----------
__global__ __launch_bounds__(256) void softmax_kernel(
    const float* __restrict__ pooled, unsigned short* __restrict__ attn)
{
  int row = blockIdx.x;                 // b*SP + w  (1640 rows)
  const float* p = pooled + (size_t)row * 4096;
  unsigned short* a = attn + (size_t)row * 4096;
  int tid = threadIdx.x;
  int lane = tid & 63, wid = tid >> 6;

  f4 v[4];
  float mx = -3.4e38f;
#pragma unroll
  for (int i = 0; i < 4; i++) {
    v[i] = *reinterpret_cast<const f4*>(&p[i * 1024 + tid * 4]);
    mx = fmaxf(mx, fmaxf(fmaxf(v[i][0], v[i][1]), fmaxf(v[i][2], v[i][3])));
  }
#pragma unroll
  for (int off = 32; off > 0; off >>= 1) mx = fmaxf(mx, __shfl_xor(mx, off, 64));
  __shared__ float redm[4];
  __shared__ float reds[4];
  if (lane == 0) redm[wid] = mx;
  __syncthreads();
  mx = fmaxf(fmaxf(redm[0], redm[1]), fmaxf(redm[2], redm[3]));

  float e[16];
  float sum = 0.f;
#pragma unroll
  for (int i = 0; i < 4; i++)
#pragma unroll
    for (int j = 0; j < 4; j++) {
      float t = __expf(v[i][j] - mx);
      e[i * 4 + j] = t;
      sum += t;
    }
#pragma unroll
  for (int off = 32; off > 0; off >>= 1) sum += __shfl_xor(sum, off, 64);
  if (lane == 0) reds[wid] = sum;
  __syncthreads();
  sum = reds[0] + reds[1] + reds[2] + reds[3];
  float inv = 1.f / sum;
#pragma unroll
  for (int i = 0; i < 4; i++) {
    u16x4 o;
#pragma unroll
    for (int j = 0; j < 4; j++) o[j] = f2bf(e[i * 4 + j] * inv);
    *reinterpret_cast<u16x4*>(&a[i * 1024 + tid * 4]) = o;
  }
}

// ---------- K4a: transpose vp [b][k][d] -> vpT [b][d][k] (bf16, LDS tiles) ----------
__global__ __launch_bounds__(256) void vpt_kernel(
    const unsigned short* __restrict__ vp, unsigned short* __restrict__ vpT)
{
  int b  = blockIdx.y;
  int kt = blockIdx.x >> 2;   // 64 tiles of 64 k
  int dt = blockIdx.x & 3;    // 4 tiles of 64 d
  int k0 = kt * 64, d0 = dt * 64;

  __shared__ unsigned short t[64][66];
  const unsigned short* src = vp + (size_t)b * S * 256;
  unsigned short* dst = vpT + (size_t)b * 256 * S;

  int tid = threadIdx.x;
  for (int s = tid; s < 512; s += 256) {     // 64 rows x 8 segs of 8 bf16
    int r = s >> 3, seg = s & 7;
    u16x8 v = *reinterpret_cast<const u16x8*>(&src[(size_t)(k0 + r) * 256 + d0 + seg * 8]);
#pragma unroll
    for (int j = 0; j < 4; j++) {            // 4B LDS writes (stride 66 not 16B-aligned)
      unsigned short* pp = &t[r][seg * 8 + j * 2];
      pp[0] = v[j * 2]; pp[1] = v[j * 2 + 1];
    }
  }
  __syncthreads();
  int d  = tid >> 2;
  int kb = (tid & 3) * 16;
  u16x8 o0, o1;
#pragma unroll
  for (int j = 0; j < 8; j++) o0[j] = t[kb + j][d];
#pragma unroll
  for (int j = 0; j < 8; j++) o1[j] = t[kb + 8 + j][d];
  *reinterpret_cast<u16x8*>(&dst[(size_t)(d0 + d) * S + k0 + kb])     = o0;
  *reinterpret_cast<u16x8*>(&dst[(size_t)(d0 + d) * S + k0 + kb + 8]) = o1;
}

// ---------- K4: PV GEMM, split-K=8, fp32 atomicAdd into ctx ----------
__global__ __launch_bounds__(256) void pv_kernel(
    const unsigned short* __restrict__ attn, const unsigned short* __restrict__ vpT,
    float* __restrict__ ctx)
{
  int bx = blockIdx.x;                 // b*4 + mt
  int b  = bx >> 2, mt = bx & 3;
  int m0 = mt * 128;                   // rows within [0,410)
  int n0 = blockIdx.y * 128;
  int k0 = blockIdx.z * 512;

  const unsigned short* Ab = attn + (size_t)b * SP * 4096;
  const unsigned short* Bb = vpT  + (size_t)b * 256 * 4096;

  __shared__ unsigned short As[128][40];
  __shared__ unsigned short Bs[128][40];

  int tid  = threadIdx.x;
  int lane = tid & 63, wid = tid >> 6;
  int wr = wid >> 1, wc = wid & 1;
  int lrow = lane & 15, kseg = lane >> 4;

  f32x4 zero4 = {0.f, 0.f, 0.f, 0.f};
  f32x4 acc[4][4];
#pragma unroll
  for (int i = 0; i < 4; i++)
#pragma unroll
    for (int j = 0; j < 4; j++) acc[i][j] = zero4;

  for (int ks = k0; ks < k0 + 512; ks += 32) {
    for (int s = tid; s < 512; s += 256) {
      int row = s >> 2, seg = s & 3;
      int m = m0 + row; m = (m > SP - 1) ? (SP - 1) : m;
      u16x8 v = *reinterpret_cast<const u16x8*>(&Ab[(size_t)m * 4096 + ks + seg * 8]);
      *reinterpret_cast<u16x8*>(&As[row][seg * 8]) = v;
    }
    for (int s = tid; s < 512; s += 256) {
      int row = s >> 2, seg = s & 3;
      u16x8 v = *reinterpret_cast<const u16x8*>(&Bb[(size_t)(n0 + row) * 4096 + ks + seg * 8]);
      *reinterpret_cast<u16x8*>(&Bs[row][seg * 8]) = v;
    }
    __syncthreads();
    bf16x8 af[4], bfr[4];
#pragma unroll
    for (int rf = 0; rf < 4; rf++)
      af[rf] = *reinterpret_cast<const bf16x8*>(&As[wr * 64 + rf * 16 + lrow][kseg * 8]);
#pragma unroll
    for (int cf = 0; cf < 4; cf++)
      bfr[cf] = *reinterpret_cast<const bf16x8*>(&Bs[wc * 64 + cf * 16 + lrow][kseg * 8]);
#pragma unroll
    for (int rf = 0; rf < 4; rf++)
#pragma unroll
      for (int cf = 0; cf < 4; cf++)
        acc[rf][cf] = mfma16(af[rf], bfr[cf], acc[rf][cf]);
    __syncthreads();
  }

  int r4 = (lane >> 4) * 4;
#pragma unroll
  for (int rf = 0; rf < 4; rf++)
#pragma unroll
    for (int cf = 0; cf < 4; cf++) {
      int n = n0 + wc * 64 + cf * 16 + lrow;
#pragma unroll
      for (int r = 0; r < 4; r++) {
        int m = m0 + wr * 64 + rf * 16 + r4 + r;
        if (m < SP) atomicAdd(&ctx[((size_t)b * SP + m) * 256 + n], acc[rf][cf][r]);
      }
    }
}

// ---------- K5: out = ctx @ wo + bo (fp32 out) ----------
__global__ __launch_bounds__(256) void out_kernel(
    const float* __restrict__ ctx, const unsigned short* __restrict__ woT,
    const float* __restrict__ bo, float* __restrict__ out)
{
  int m0 = blockIdx.x * 128;           // over B*SP = 1640
  int n0 = blockIdx.y * 128;
  const int M = B * SP;

  __shared__ unsigned short As[128][40];
  __shared__ unsigned short Bs[128][40];

  int tid  = threadIdx.x;
  int lane = tid & 63, wid = tid >> 6;
  int wr = wid >> 1, wc = wid & 1;
  int lrow = lane & 15, kseg = lane >> 4;

  f32x4 zero4 = {0.f, 0.f, 0.f, 0.f};
  f32x4 acc[4][4];
#pragma unroll
  for (int i = 0; i < 4; i++)
#pragma unroll
    for (int j = 0; j < 4; j++) acc[i][j] = zero4;

  for (int ks = 0; ks < 256; ks += 32) {
    for (int s = tid; s < 1024; s += 256) {
      int row = s >> 3, seg = s & 7;
      int m = m0 + row; m = (m > M - 1) ? (M - 1) : m;
      f4 v = *reinterpret_cast<const f4*>(&ctx[(size_t)m * 256 + ks + seg * 4]);
      u16x4 h;
      h[0] = f2bf(v[0]); h[1] = f2bf(v[1]); h[2] = f2bf(v[2]); h[3] = f2bf(v[3]);
      *reinterpret_cast<u16x4*>(&As[row][seg * 4]) = h;
    }
    for (int s = tid; s < 512; s += 256) {
      int row = s >> 2, seg = s & 3;
      u16x8 v = *reinterpret_cast<const u16x8*>(&woT[(size_t)(n0 + row) * 256 + ks + seg * 8]);
      *reinterpret_cast<u16x8*>(&Bs[row][seg * 8]) = v;
    }
    __syncthreads();
    bf16x8 af[4], bfr[4];
#pragma unroll
    for (int rf = 0; rf < 4; rf++)
      af[rf] = *reinterpret_cast<const bf16x8*>(&As[wr * 64 + rf * 16 + lrow][kseg * 8]);
#pragma unroll
    for (int cf = 0; cf < 4; cf++)
      bfr[cf] = *reinterpret_cast<const bf16x8*>(&Bs[wc * 64 + cf * 16 + lrow][kseg * 8]);
#pragma unroll
    for (int rf = 0; rf < 4; rf++)
#pragma unroll
      for (int cf = 0; cf < 4; cf++)
        acc[rf][cf] = mfma16(af[rf], bfr[cf], acc[rf][cf]);
    __syncthreads();
  }

  int r4 = (lane >> 4) * 4;
#pragma unroll
  for (int rf = 0; rf < 4; rf++)
#pragma unroll
    for (int cf = 0; cf < 4; cf++) {
      int n = n0 + wc * 64 + cf * 16 + lrow;
      float bv_ = bo[n];
#pragma unroll
      for (int r = 0; r < 4; r++) {
        int m = m0 + wr * 64 + rf * 16 + r4 + r;
        if (m < M) out[(size_t)m * 256 + n] = acc[rf][cf][r] + bv_;
      }
    }
}

// ---------- launch ----------
extern "C" void kernel_launch(void* const* d_in, const int* in_sizes, int n_in,
                              void* d_out, int out_size, void* d_ws, size_t ws_size,
                              hipStream_t stream)
{
  const float* v  = (const float*)d_in[0];
  const float* k  = (const float*)d_in[1];
  const float* q  = (const float*)d_in[2];
  const float* wq = (const float*)d_in[3];
  const float* bq = (const float*)d_in[4];
  const float* wk = (const float*)d_in[5];
  const float* bk = (const float*)d_in[6];
  const float* wv = (const float*)d_in[7];
  const float* bv = (const float*)d_in[8];
  const float* wo = (const float*)d_in[9];
  const float* bo = (const float*)d_in[10];
  float* out = (float*)d_out;

  char* ws = (char*)d_ws;
  size_t off = 0;
  auto alloc = [&](size_t bytes) -> void* {
    void* p = ws + off;
    off += (bytes + 255) & ~(size_t)255;
    return p;
  };
  unsigned short* qp   = (unsigned short*)alloc((size_t)B * S * D * 2);     // 8 MB
  unsigned short* kp   = (unsigned short*)alloc((size_t)B * S * D * 2);     // 8 MB
  unsigned short* vp   = (unsigned short*)alloc((size_t)B * S * D * 2);     // 8 MB
  unsigned short* vpT  = (unsigned short*)alloc((size_t)B * S * D * 2);     // 8 MB
  unsigned short* wt   = (unsigned short*)alloc((size_t)4 * 256 * 256 * 2); // 0.5 MB
  float*          pooled = (float*)alloc((size_t)B * SP * 4096 * 4);        // 26.9 MB
  unsigned short* attn = (unsigned short*)alloc((size_t)B * SP * 4096 * 2); // 13.4 MB
  float*          ctx  = (float*)alloc((size_t)B * SP * D * 4);             // 1.7 MB

  wt_trans_kernel<<<1024, 256, 0, stream>>>(wq, wk, wv, wo, wt);
  proj_kernel<<<dim3(128, 2, 3), 256, 0, stream>>>(q, k, v, wt, bq, bk, bv, qp, kp, vp);
  scores_pool_kernel<<<dim3(32, 26, 4), 512, 0, stream>>>(qp, kp, pooled);
  softmax_kernel<<<B * SP, 256, 0, stream>>>(pooled, attn);
  vpt_kernel<<<dim3(256, 4), 256, 0, stream>>>(vp, vpT);
  hipMemsetAsync(ctx, 0, (size_t)B * SP * D * 4, stream);
  pv_kernel<<<dim3(16, 2, 8), 256, 0, stream>>>(attn, vpT, ctx);
  out_kernel<<<dim3(13, 2), 256, 0, stream>>>(ctx, wt + 3 * 65536, bo, out);
}

// Round 2
// 257.492 us; speedup vs baseline: 1.2654x; 1.2654x over previous
//
#include <hip/hip_runtime.h>
#include <hip/hip_bf16.h>
#include <stdint.h>

// ---------- types ----------
typedef __attribute__((ext_vector_type(8))) short          bf16x8;
typedef __attribute__((ext_vector_type(4))) float          f32x4;
typedef __attribute__((ext_vector_type(4))) float          f4;
typedef __attribute__((ext_vector_type(8))) unsigned short u16x8;
typedef __attribute__((ext_vector_type(4))) unsigned short u16x4;

#define DEVINL __device__ __forceinline__

static constexpr int B  = 4;
static constexpr int S  = 4096;
static constexpr int D  = 256;
static constexpr int SP = 410;   // ceil(4096/10), SAME pooling, pad_lo = 2

DEVINL unsigned short f2bf(float x) {
  union { float f; unsigned u; } v; v.f = x;
  unsigned r = v.u + 0x7FFFu + ((v.u >> 16) & 1u);   // round-to-nearest-even
  return (unsigned short)(r >> 16);
}

DEVINL f32x4 mfma16(bf16x8 a, bf16x8 b, f32x4 c) {
  return __builtin_amdgcn_mfma_f32_16x16x32_bf16(a, b, c, 0, 0, 0);
}

typedef const __attribute__((address_space(1))) void* gas_t;
typedef __attribute__((address_space(3))) void*       las_t;
DEVINL void gload16(const void* g, void* l) {
  __builtin_amdgcn_global_load_lds((gas_t)g, (las_t)l, 16, 0, 0);
}

// ---------- K0: transpose + convert the 4 weight matrices to bf16 [n][k] ----------
__global__ __launch_bounds__(256) void wt_trans_kernel(
    const float* __restrict__ wq, const float* __restrict__ wk,
    const float* __restrict__ wv, const float* __restrict__ wo,
    unsigned short* __restrict__ wt)
{
  int idx = blockIdx.x * 256 + threadIdx.x;   // 4 * 256 * 256
  int mat = idx >> 16;
  int r   = idx & 65535;
  int n   = r >> 8;
  int k   = r & 255;
  const float* w = (mat == 0) ? wq : (mat == 1) ? wk : (mat == 2) ? wv : wo;
  wt[idx] = f2bf(w[k * 256 + n]);             // wt[mat][n][k] = w[k][n]
}

// ---------- K1: fused QKV projections (bf16 MFMA, fp32 A converted in staging) ----------
__global__ __launch_bounds__(256) void proj_kernel(
    const float* __restrict__ xq, const float* __restrict__ xk, const float* __restrict__ xv,
    const unsigned short* __restrict__ wt,
    const float* __restrict__ bq, const float* __restrict__ bk, const float* __restrict__ bv,
    unsigned short* __restrict__ qp, unsigned short* __restrict__ kp, unsigned short* __restrict__ vp)
{
  int z = blockIdx.z;
  const float* A            = (z == 0) ? xq : (z == 1) ? xk : xv;
  const unsigned short* W   = wt + z * 65536;
  const float* bias         = (z == 0) ? bq : (z == 1) ? bk : bv;
  unsigned short* Out       = (z == 0) ? qp : (z == 1) ? kp : vp;

  int m0 = blockIdx.x * 128;
  int n0 = blockIdx.y * 128;

  __shared__ unsigned short As[128][40];
  __shared__ unsigned short Bs[128][40];

  int tid  = threadIdx.x;
  int lane = tid & 63, wid = tid >> 6;
  int wr = wid >> 1, wc = wid & 1;
  int lrow = lane & 15, kseg = lane >> 4;

  f32x4 zero4 = {0.f, 0.f, 0.f, 0.f};
  f32x4 acc[4][4];
#pragma unroll
  for (int i = 0; i < 4; i++)
#pragma unroll
    for (int j = 0; j < 4; j++) acc[i][j] = zero4;

  for (int ks = 0; ks < 256; ks += 32) {
    for (int s = tid; s < 1024; s += 256) {
      int row = s >> 3, seg = s & 7;
      f4 v = *reinterpret_cast<const f4*>(&A[(size_t)(m0 + row) * 256 + ks + seg * 4]);
      u16x4 h;
      h[0] = f2bf(v[0]); h[1] = f2bf(v[1]); h[2] = f2bf(v[2]); h[3] = f2bf(v[3]);
      *reinterpret_cast<u16x4*>(&As[row][seg * 4]) = h;
    }
    for (int s = tid; s < 512; s += 256) {
      int row = s >> 2, seg = s & 3;
      u16x8 v = *reinterpret_cast<const u16x8*>(&W[(size_t)(n0 + row) * 256 + ks + seg * 8]);
      *reinterpret_cast<u16x8*>(&Bs[row][seg * 8]) = v;
    }
    __syncthreads();
    bf16x8 af[4], bfr[4];
#pragma unroll
    for (int rf = 0; rf < 4; rf++)
      af[rf] = *reinterpret_cast<const bf16x8*>(&As[wr * 64 + rf * 16 + lrow][kseg * 8]);
#pragma unroll
    for (int cf = 0; cf < 4; cf++)
      bfr[cf] = *reinterpret_cast<const bf16x8*>(&Bs[wc * 64 + cf * 16 + lrow][kseg * 8]);
#pragma unroll
    for (int rf = 0; rf < 4; rf++)
#pragma unroll
      for (int cf = 0; cf < 4; cf++)
        acc[rf][cf] = mfma16(af[rf], bfr[cf], acc[rf][cf]);
    __syncthreads();
  }

  int r4 = (lane >> 4) * 4;
#pragma unroll
  for (int rf = 0; rf < 4; rf++)
#pragma unroll
    for (int cf = 0; cf < 4; cf++) {
      int n = n0 + wc * 64 + cf * 16 + lrow;
      float bv_ = bias[n];
#pragma unroll
      for (int r = 0; r < 4; r++) {
        int m = m0 + wr * 64 + rf * 16 + r4 + r;
        Out[(size_t)m * 256 + n] = f2bf(acc[rf][cf][r] + bv_);
      }
    }
}

// ---------- K2: scores GEMM + fused max-pool (v2) ----------
// Block: 256 q-rows (25 windows, qb = 250*wb - 2) x 128 n-cols, BK=64.
// global_load_lds staging with XOR-swizzled source; in-register pair-max pooling
// (2-row pairs never straddle a 10-row window since windows start at even rows).
__global__ __launch_bounds__(512, 4) void scores_pool_kernel(
    const unsigned short* __restrict__ qp, const unsigned short* __restrict__ kp,
    float* __restrict__ pooled)
{
  int b  = blockIdx.z;
  int wb = blockIdx.y;              // 0..16
  int nb = blockIdx.x;              // 0..31
  int w0 = wb * 25;
  int qb = w0 * 10 - 2;
  int n0 = nb * 128;
  int nwin = SP - w0; if (nwin > 25) nwin = 25;

  __shared__ __align__(16) union SM {
    struct { char A[32768]; char Bm[16384]; } st;   // A: 256x64 bf16, B: 128x64 bf16
    float pm[9216];                                 // 128 pairs x stride 72 (f32)
  } sm;
  char* Asm = sm.st.A;
  char* Bsm = sm.st.Bm;

  const unsigned short* qpb = qp + (size_t)b * S * 256;
  const unsigned short* kpb = kp + (size_t)b * S * 256;

  int tid  = threadIdx.x;
  int lane = tid & 63, wid = tid >> 6;   // 8 waves
  int wr = wid >> 1, wc = wid & 1;       // 4x2 wave grid, each 64x64
  int lrow = lane & 15, kseg = lane >> 4;

  f32x4 zero4 = {0.f, 0.f, 0.f, 0.f};
  f32x4 acc[4][4];
#pragma unroll
  for (int i = 0; i < 4; i++)
#pragma unroll
    for (int j = 0; j < 4; j++) acc[i][j] = zero4;

  for (int ks = 0; ks < 4; ++ks) {
    // stage A: 32 KB = 32 wave-insts, 4 per wave. LDS linear; source pre-swizzled.
#pragma unroll
    for (int i = 0; i < 4; ++i) {
      int inst = wid * 4 + i;
      int sg   = inst * 64 + lane;
      int row  = sg >> 3;              // 0..255
      int c16  = sg & 7;               // 16B-column within 128B row
      int q = qb + row; q = (q < 0) ? 0 : ((q > S - 1) ? (S - 1) : q);
      const char* g = (const char*)qpb + ((size_t)q << 9) + (ks << 7) + ((c16 ^ (row & 7)) << 4);
      gload16(g, Asm + inst * 1024);
    }
    // stage B: 16 KB = 16 wave-insts, 2 per wave.
#pragma unroll
    for (int i = 0; i < 2; ++i) {
      int inst = wid * 2 + i;
      int sg   = inst * 64 + lane;
      int row  = sg >> 3;              // n-local 0..127
      int c16  = sg & 7;
      const char* g = (const char*)kpb + ((size_t)(n0 + row) << 9) + (ks << 7) + ((c16 ^ (row & 7)) << 4);
      gload16(g, Bsm + inst * 1024);
    }
    __syncthreads();
#pragma unroll
    for (int kk = 0; kk < 2; ++kk) {
      bf16x8 af[4], bfr[4];
#pragma unroll
      for (int mi = 0; mi < 4; ++mi) {
        int R   = wr * 64 + mi * 16 + lrow;
        int c16 = (kk * 4 + kseg) ^ (R & 7);
        af[mi] = *reinterpret_cast<const bf16x8*>(Asm + R * 128 + c16 * 16);
      }
#pragma unroll
      for (int cf = 0; cf < 4; ++cf) {
        int nl  = wc * 64 + cf * 16 + lrow;
        int c16 = (kk * 4 + kseg) ^ (nl & 7);
        bfr[cf] = *reinterpret_cast<const bf16x8*>(Bsm + nl * 128 + c16 * 16);
      }
#pragma unroll
      for (int mi = 0; mi < 4; ++mi)
#pragma unroll
        for (int cf = 0; cf < 4; ++cf)
          acc[mi][cf] = mfma16(af[mi], bfr[cf], acc[mi][cf]);
    }
    __syncthreads();
  }

  // ---- pooling: in-register pair-max -> LDS [128 pairs][72] f32 -> 5-way window max
  int h = kseg;   // lane>>4 : row sub-block (rows 4h..4h+3 per fragment)
#pragma unroll
  for (int c = 0; c < 2; ++c) {
    __syncthreads();
    if (wc == c) {
#pragma unroll
      for (int mi = 0; mi < 4; ++mi) {
        int p = wr * 32 + mi * 8 + h * 2;     // pair index (row R0/2)
#pragma unroll
        for (int cf = 0; cf < 4; ++cf) {
          int col = cf * 16 + lrow;
          sm.pm[p * 72 + col]       = fmaxf(acc[mi][cf][0], acc[mi][cf][1]);
          sm.pm[(p + 1) * 72 + col] = fmaxf(acc[mi][cf][2], acc[mi][cf][3]);
        }
      }
    }
    __syncthreads();
    for (int s = tid; s < 1600; s += 512) {
      int j = s >> 6, col = s & 63;
      if (j < nwin) {
        float m = -3.4e38f;
#pragma unroll
        for (int i = 0; i < 5; ++i) {
          int p  = 5 * j + i;
          int q0 = qb + 2 * p;                // first row of pair (even, pairs atomically valid)
          if (q0 >= 0 && q0 < S) m = fmaxf(m, sm.pm[p * 72 + col]);
        }
        pooled[((size_t)b * SP + w0 + j) * 4096 + n0 + c * 64 + col] = m * 0.0625f;
      }
    }
  }
}

// ---------- K3: row softmax (4096 cols), fp32 in, bf16 out ----------
__global__ __launch_bounds__(256) void softmax_kernel(
    const float* __restrict__ pooled, unsigned short* __restrict__ attn)
{
  int row = blockIdx.x;
  const float* p = pooled + (size_t)row * 4096;
  unsigned short* a = attn + (size_t)row * 4096;
  int tid = threadIdx.x;
  int lane = tid & 63, wid = tid >> 6;

  f4 v[4];
  float mx = -3.4e38f;
#pragma unroll
  for (int i = 0; i < 4; i++) {
    v[i] = *reinterpret_cast<const f4*>(&p[i * 1024 + tid * 4]);
    mx = fmaxf(mx, fmaxf(fmaxf(v[i][0], v[i][1]), fmaxf(v[i][2], v[i][3])));
  }
#pragma unroll
  for (int off = 32; off > 0; off >>= 1) mx = fmaxf(mx, __shfl_xor(mx, off, 64));
  __shared__ float redm[4];
  __shared__ float reds[4];
  if (lane == 0) redm[wid] = mx;
  __syncthreads();
  mx = fmaxf(fmaxf(redm[0], redm[1]), fmaxf(redm[2], redm[3]));

  float e[16];
  float sum = 0.f;
#pragma unroll
  for (int i = 0; i < 4; i++)
#pragma unroll
    for (int j = 0; j < 4; j++) {
      float t = __expf(v[i][j] - mx);
      e[i * 4 + j] = t;
      sum += t;
    }
#pragma unroll
  for (int off = 32; off > 0; off >>= 1) sum += __shfl_xor(sum, off, 64);
  if (lane == 0) reds[wid] = sum;
  __syncthreads();
  sum = reds[0] + reds[1] + reds[2] + reds[3];
  float inv = 1.f / sum;
#pragma unroll
  for (int i = 0; i < 4; i++) {
    u16x4 o;
#pragma unroll
    for (int j = 0; j < 4; j++) o[j] = f2bf(e[i * 4 + j] * inv);
    *reinterpret_cast<u16x4*>(&a[i * 1024 + tid * 4]) = o;
  }
}

// ---------- K4a: transpose vp [b][k][d] -> vpT [b][d][k] ----------
__global__ __launch_bounds__(256) void vpt_kernel(
    const unsigned short* __restrict__ vp, unsigned short* __restrict__ vpT)
{
  int b  = blockIdx.y;
  int kt = blockIdx.x >> 2;
  int dt = blockIdx.x & 3;
  int k0 = kt * 64, d0 = dt * 64;

  __shared__ unsigned short t[64][66];
  const unsigned short* src = vp + (size_t)b * S * 256;
  unsigned short* dst = vpT + (size_t)b * 256 * S;

  int tid = threadIdx.x;
  for (int s = tid; s < 512; s += 256) {
    int r = s >> 3, seg = s & 7;
    u16x8 v = *reinterpret_cast<const u16x8*>(&src[(size_t)(k0 + r) * 256 + d0 + seg * 8]);
#pragma unroll
    for (int j = 0; j < 4; j++) {
      unsigned short* pp = &t[r][seg * 8 + j * 2];
      pp[0] = v[j * 2]; pp[1] = v[j * 2 + 1];
    }
  }
  __syncthreads();
  int d  = tid >> 2;
  int kb = (tid & 3) * 16;
  u16x8 o0, o1;
#pragma unroll
  for (int j = 0; j < 8; j++) o0[j] = t[kb + j][d];
#pragma unroll
  for (int j = 0; j < 8; j++) o1[j] = t[kb + 8 + j][d];
  *reinterpret_cast<u16x8*>(&dst[(size_t)(d0 + d) * S + k0 + kb])     = o0;
  *reinterpret_cast<u16x8*>(&dst[(size_t)(d0 + d) * S + k0 + kb + 8]) = o1;
}

// ---------- K4: PV GEMM, split-K=8, partials to ws (no atomics) ----------
__global__ __launch_bounds__(256) void pv_kernel(
    const unsigned short* __restrict__ attn, const unsigned short* __restrict__ vpT,
    float* __restrict__ part)
{
  int bx = blockIdx.x;
  int b  = bx >> 2, mt = bx & 3;
  int m0 = mt * 128;
  int n0 = blockIdx.y * 128;
  int kz = blockIdx.z;
  int k0 = kz * 512;

  const unsigned short* Ab = attn + (size_t)b * SP * 4096;
  const unsigned short* Bb = vpT  + (size_t)b * 256 * 4096;
  float* Pz = part + (size_t)kz * 419840;   // 1640*256

  __shared__ unsigned short As[128][40];
  __shared__ unsigned short Bs[128][40];

  int tid  = threadIdx.x;
  int lane = tid & 63, wid = tid >> 6;
  int wr = wid >> 1, wc = wid & 1;
  int lrow = lane & 15, kseg = lane >> 4;

  f32x4 zero4 = {0.f, 0.f, 0.f, 0.f};
  f32x4 acc[4][4];
#pragma unroll
  for (int i = 0; i < 4; i++)
#pragma unroll
    for (int j = 0; j < 4; j++) acc[i][j] = zero4;

  for (int ks = k0; ks < k0 + 512; ks += 32) {
    for (int s = tid; s < 512; s += 256) {
      int row = s >> 2, seg = s & 3;
      int m = m0 + row; m = (m > SP - 1) ? (SP - 1) : m;
      u16x8 v = *reinterpret_cast<const u16x8*>(&Ab[(size_t)m * 4096 + ks + seg * 8]);
      *reinterpret_cast<u16x8*>(&As[row][seg * 8]) = v;
    }
    for (int s = tid; s < 512; s += 256) {
      int row = s >> 2, seg = s & 3;
      u16x8 v = *reinterpret_cast<const u16x8*>(&Bb[(size_t)(n0 + row) * 4096 + ks + seg * 8]);
      *reinterpret_cast<u16x8*>(&Bs[row][seg * 8]) = v;
    }
    __syncthreads();
    bf16x8 af[4], bfr[4];
#pragma unroll
    for (int rf = 0; rf < 4; rf++)
      af[rf] = *reinterpret_cast<const bf16x8*>(&As[wr * 64 + rf * 16 + lrow][kseg * 8]);
#pragma unroll
    for (int cf = 0; cf < 4; cf++)
      bfr[cf] = *reinterpret_cast<const bf16x8*>(&Bs[wc * 64 + cf * 16 + lrow][kseg * 8]);
#pragma unroll
    for (int rf = 0; rf < 4; rf++)
#pragma unroll
      for (int cf = 0; cf < 4; cf++)
        acc[rf][cf] = mfma16(af[rf], bfr[cf], acc[rf][cf]);
    __syncthreads();
  }

  int r4 = (lane >> 4) * 4;
#pragma unroll
  for (int rf = 0; rf < 4; rf++)
#pragma unroll
    for (int cf = 0; cf < 4; cf++) {
      int n = n0 + wc * 64 + cf * 16 + lrow;
#pragma unroll
      for (int r = 0; r < 4; r++) {
        int m = m0 + wr * 64 + rf * 16 + r4 + r;
        if (m < SP) Pz[((size_t)b * SP + m) * 256 + n] = acc[rf][cf][r];
      }
    }
}

// ---------- K5: out = (sum_z part_z) @ wo + bo ----------
__global__ __launch_bounds__(256) void out_kernel(
    const float* __restrict__ part, const unsigned short* __restrict__ woT,
    const float* __restrict__ bo, float* __restrict__ out)
{
  int m0 = blockIdx.x * 128;
  int n0 = blockIdx.y * 128;
  const int M = B * SP;

  __shared__ unsigned short As[128][40];
  __shared__ unsigned short Bs[128][40];

  int tid  = threadIdx.x;
  int lane = tid & 63, wid = tid >> 6;
  int wr = wid >> 1, wc = wid & 1;
  int lrow = lane & 15, kseg = lane >> 4;

  f32x4 zero4 = {0.f, 0.f, 0.f, 0.f};
  f32x4 acc[4][4];
#pragma unroll
  for (int i = 0; i < 4; i++)
#pragma unroll
    for (int j = 0; j < 4; j++) acc[i][j] = zero4;

  for (int ks = 0; ks < 256; ks += 32) {
    for (int s = tid; s < 1024; s += 256) {
      int row = s >> 3, seg = s & 7;
      int m = m0 + row; m = (m > M - 1) ? (M - 1) : m;
      const float* p0 = part + (size_t)m * 256 + ks + seg * 4;
      f4 a = {0.f, 0.f, 0.f, 0.f};
#pragma unroll
      for (int z = 0; z < 8; ++z) a += *reinterpret_cast<const f4*>(p0 + (size_t)z * 419840);
      u16x4 hh;
      hh[0] = f2bf(a[0]); hh[1] = f2bf(a[1]); hh[2] = f2bf(a[2]); hh[3] = f2bf(a[3]);
      *reinterpret_cast<u16x4*>(&As[row][seg * 4]) = hh;
    }
    for (int s = tid; s < 512; s += 256) {
      int row = s >> 2, seg = s & 3;
      u16x8 v = *reinterpret_cast<const u16x8*>(&woT[(size_t)(n0 + row) * 256 + ks + seg * 8]);
      *reinterpret_cast<u16x8*>(&Bs[row][seg * 8]) = v;
    }
    __syncthreads();
    bf16x8 af[4], bfr[4];
#pragma unroll
    for (int rf = 0; rf < 4; rf++)
      af[rf] = *reinterpret_cast<const bf16x8*>(&As[wr * 64 + rf * 16 + lrow][kseg * 8]);
#pragma unroll
    for (int cf = 0; cf < 4; cf++)
      bfr[cf] = *reinterpret_cast<const bf16x8*>(&Bs[wc * 64 + cf * 16 + lrow][kseg * 8]);
#pragma unroll
    for (int rf = 0; rf < 4; rf++)
#pragma unroll
      for (int cf = 0; cf < 4; cf++)
        acc[rf][cf] = mfma16(af[rf], bfr[cf], acc[rf][cf]);
    __syncthreads();
  }

  int r4 = (lane >> 4) * 4;
#pragma unroll
  for (int rf = 0; rf < 4; rf++)
#pragma unroll
    for (int cf = 0; cf < 4; cf++) {
      int n = n0 + wc * 64 + cf * 16 + lrow;
      float bv_ = bo[n];
#pragma unroll
      for (int r = 0; r < 4; r++) {
        int m = m0 + wr * 64 + rf * 16 + r4 + r;
        if (m < M) out[(size_t)m * 256 + n] = acc[rf][cf][r] + bv_;
      }
    }
}

// ---------- launch ----------
extern "C" void kernel_launch(void* const* d_in, const int* in_sizes, int n_in,
                              void* d_out, int out_size, void* d_ws, size_t ws_size,
                              hipStream_t stream)
{
  const float* v  = (const float*)d_in[0];
  const float* k  = (const float*)d_in[1];
  const float* q  = (const float*)d_in[2];
  const float* wq = (const float*)d_in[3];
  const float* bq = (const float*)d_in[4];
  const float* wk = (const float*)d_in[5];
  const float* bk = (const float*)d_in[6];
  const float* wv = (const float*)d_in[7];
  const float* bv = (const float*)d_in[8];
  const float* wo = (const float*)d_in[9];
  const float* bo = (const float*)d_in[10];
  float* out = (float*)d_out;

  char* ws = (char*)d_ws;
  size_t off = 0;
  auto alloc = [&](size_t bytes) -> void* {
    void* p = ws + off;
    off += (bytes + 255) & ~(size_t)255;
    return p;
  };
  unsigned short* qp   = (unsigned short*)alloc((size_t)B * S * D * 2);     // 8 MB
  unsigned short* kp   = (unsigned short*)alloc((size_t)B * S * D * 2);     // 8 MB
  unsigned short* vp   = (unsigned short*)alloc((size_t)B * S * D * 2);     // 8 MB
  unsigned short* vpT  = (unsigned short*)alloc((size_t)B * S * D * 2);     // 8 MB
  unsigned short* wt   = (unsigned short*)alloc((size_t)4 * 256 * 256 * 2); // 0.5 MB
  float*          pooled = (float*)alloc((size_t)B * SP * 4096 * 4);        // 26.9 MB
  unsigned short* attn = (unsigned short*)alloc((size_t)B * SP * 4096 * 2); // 13.4 MB
  float*          part = pooled;    // pv partials reuse pooled (dead after softmax); 8*1.68 MB <= 26.9 MB

  wt_trans_kernel<<<1024, 256, 0, stream>>>(wq, wk, wv, wo, wt);
  proj_kernel<<<dim3(128, 2, 3), 256, 0, stream>>>(q, k, v, wt, bq, bk, bv, qp, kp, vp);
  scores_pool_kernel<<<dim3(32, 17, 4), 512, 0, stream>>>(qp, kp, pooled);
  softmax_kernel<<<B * SP, 256, 0, stream>>>(pooled, attn);
  vpt_kernel<<<dim3(256, 4), 256, 0, stream>>>(vp, vpT);
  pv_kernel<<<dim3(16, 2, 8), 256, 0, stream>>>(attn, vpT, part);
  out_kernel<<<dim3(13, 2), 256, 0, stream>>>(part, wt + 3 * 65536, bo, out);
}

// Round 3
// 230.196 us; speedup vs baseline: 1.4155x; 1.1186x over previous
//
#include <hip/hip_runtime.h>
#include <hip/hip_bf16.h>
#include <stdint.h>

// ---------- types ----------
typedef __attribute__((ext_vector_type(8))) short          bf16x8;
typedef __attribute__((ext_vector_type(4))) float          f32x4;
typedef __attribute__((ext_vector_type(4))) float          f4;
typedef __attribute__((ext_vector_type(8))) unsigned short u16x8;
typedef __attribute__((ext_vector_type(4))) unsigned short u16x4;

#define DEVINL __device__ __forceinline__

static constexpr int B  = 4;
static constexpr int S  = 4096;
static constexpr int D  = 256;
static constexpr int SP = 410;   // ceil(4096/10), SAME pooling, pad_lo = 2
static constexpr int KZ = 16;    // pv split-K factor
static constexpr int MO = B * SP;                 // 1640
static constexpr size_t PSLICE = (size_t)MO * D;  // 419840

DEVINL unsigned short f2bf(float x) {
  union { float f; unsigned u; } v; v.f = x;
  unsigned r = v.u + 0x7FFFu + ((v.u >> 16) & 1u);   // round-to-nearest-even
  return (unsigned short)(r >> 16);
}

DEVINL f32x4 mfma16(bf16x8 a, bf16x8 b, f32x4 c) {
  return __builtin_amdgcn_mfma_f32_16x16x32_bf16(a, b, c, 0, 0, 0);
}

typedef const __attribute__((address_space(1))) void* gas_t;
typedef __attribute__((address_space(3))) void*       las_t;
DEVINL void gload16(const void* g, void* l) {
  __builtin_amdgcn_global_load_lds((gas_t)g, (las_t)l, 16, 0, 0);
}

// ---------- K0: transpose + convert the 4 weight matrices to bf16 [n][k] ----------
__global__ __launch_bounds__(256) void wt_trans_kernel(
    const float* __restrict__ wq, const float* __restrict__ wk,
    const float* __restrict__ wv, const float* __restrict__ wo,
    unsigned short* __restrict__ wt)
{
  int idx = blockIdx.x * 256 + threadIdx.x;   // 4 * 256 * 256
  int mat = idx >> 16;
  int r   = idx & 65535;
  int n   = r >> 8;
  int k   = r & 255;
  const float* w = (mat == 0) ? wq : (mat == 1) ? wk : (mat == 2) ? wv : wo;
  wt[idx] = f2bf(w[k * 256 + n]);             // wt[mat][n][k] = w[k][n]
}

// ---------- K0b: streaming f32 -> bf16 for q,k,v ----------
__global__ __launch_bounds__(256) void cvt_kernel(
    const float* __restrict__ xq, const float* __restrict__ xk, const float* __restrict__ xv,
    unsigned short* __restrict__ oq, unsigned short* __restrict__ ok, unsigned short* __restrict__ ov)
{
  int z = blockIdx.y;
  const float* x    = (z == 0) ? xq : (z == 1) ? xk : xv;
  unsigned short* o = (z == 0) ? oq : (z == 1) ? ok : ov;
  size_t i = ((size_t)blockIdx.x * 256 + threadIdx.x) * 8;
  f4 a = *reinterpret_cast<const f4*>(x + i);
  f4 c = *reinterpret_cast<const f4*>(x + i + 4);
  u16x8 h;
  h[0] = f2bf(a[0]); h[1] = f2bf(a[1]); h[2] = f2bf(a[2]); h[3] = f2bf(a[3]);
  h[4] = f2bf(c[0]); h[5] = f2bf(c[1]); h[6] = f2bf(c[2]); h[7] = f2bf(c[3]);
  *reinterpret_cast<u16x8*>(o + i) = h;
}

// ---------- K1: QKV projection GEMM (pure bf16, stage-ahead dbuf) ----------
// C[m][n] = sum_k X_bf16[m][k] * WT_bf16[n][k] + bias[n] -> bf16
__global__ __launch_bounds__(512) void proj_kernel(
    const unsigned short* __restrict__ xq, const unsigned short* __restrict__ xk,
    const unsigned short* __restrict__ xv, const unsigned short* __restrict__ wt,
    const float* __restrict__ bq, const float* __restrict__ bk, const float* __restrict__ bv,
    unsigned short* __restrict__ qp, unsigned short* __restrict__ kp, unsigned short* __restrict__ vp)
{
  int z = blockIdx.z;
  const unsigned short* X = (z == 0) ? xq : (z == 1) ? xk : xv;
  const unsigned short* W = wt + z * 65536;
  const float* bias       = (z == 0) ? bq : (z == 1) ? bk : bv;
  unsigned short* Out     = (z == 0) ? qp : (z == 1) ? kp : vp;

  int m0 = blockIdx.x * 256;
  int n0 = blockIdx.y * 128;

  __shared__ __align__(16) struct { char A[2][32768]; char Bm[2][16384]; } sm;

  const char* Xc = (const char*)X;
  const char* Wc = (const char*)W;

  int tid  = threadIdx.x;
  int lane = tid & 63, wid = tid >> 6;
  int wr = wid >> 1, wc = wid & 1;       // 4x2 waves, 64x64 each
  int lrow = lane & 15, kseg = lane >> 4;

  f32x4 zero4 = {0.f, 0.f, 0.f, 0.f};
  f32x4 acc[4][4];
#pragma unroll
  for (int i = 0; i < 4; i++)
#pragma unroll
    for (int j = 0; j < 4; j++) acc[i][j] = zero4;

  auto stage = [&](int t, int buf) {
#pragma unroll
    for (int i = 0; i < 4; ++i) {                   // A: 256 rows x 64k
      int inst = wid * 4 + i;
      int sg   = inst * 64 + lane;
      int row  = sg >> 3, c16 = sg & 7;
      gload16(Xc + ((size_t)(m0 + row) << 9) + (t << 7) + ((c16 ^ (row & 7)) << 4),
              sm.A[buf] + inst * 1024);
    }
#pragma unroll
    for (int i = 0; i < 2; ++i) {                   // B: 128 rows x 64k
      int inst = wid * 2 + i;
      int sg   = inst * 64 + lane;
      int row  = sg >> 3, c16 = sg & 7;
      gload16(Wc + ((size_t)(n0 + row) << 9) + (t << 7) + ((c16 ^ (row & 7)) << 4),
              sm.Bm[buf] + inst * 1024);
    }
  };

  stage(0, 0);
  __syncthreads();
#pragma unroll
  for (int t = 0; t < 4; ++t) {
    int cur = t & 1;
    if (t < 3) stage(t + 1, cur ^ 1);
    const char* Asm = sm.A[cur];
    const char* Bsm = sm.Bm[cur];
#pragma unroll
    for (int kk = 0; kk < 2; ++kk) {
      bf16x8 af[4], bfr[4];
#pragma unroll
      for (int mi = 0; mi < 4; ++mi) {
        int R = wr * 64 + mi * 16 + lrow;
        int c16 = (kk * 4 + kseg) ^ (R & 7);
        af[mi] = *reinterpret_cast<const bf16x8*>(Asm + R * 128 + c16 * 16);
      }
#pragma unroll
      for (int cf = 0; cf < 4; ++cf) {
        int nl = wc * 64 + cf * 16 + lrow;
        int c16 = (kk * 4 + kseg) ^ (nl & 7);
        bfr[cf] = *reinterpret_cast<const bf16x8*>(Bsm + nl * 128 + c16 * 16);
      }
#pragma unroll
      for (int mi = 0; mi < 4; ++mi)
#pragma unroll
        for (int cf = 0; cf < 4; ++cf)
          acc[mi][cf] = mfma16(af[mi], bfr[cf], acc[mi][cf]);
    }
    __syncthreads();
  }

  int r4 = kseg * 4;
#pragma unroll
  for (int mi = 0; mi < 4; mi++)
#pragma unroll
    for (int cf = 0; cf < 4; cf++) {
      int n = n0 + wc * 64 + cf * 16 + lrow;
      float bv_ = bias[n];
#pragma unroll
      for (int r = 0; r < 4; r++) {
        int m = m0 + wr * 64 + mi * 16 + r4 + r;
        Out[(size_t)m * 256 + n] = f2bf(acc[mi][cf][r] + bv_);
      }
    }
}

// ---------- K2: scores GEMM + fused max-pool (stage-ahead dbuf) ----------
__global__ __launch_bounds__(512) void scores_pool_kernel(
    const unsigned short* __restrict__ qp, const unsigned short* __restrict__ kp,
    float* __restrict__ pooled)
{
  int b  = blockIdx.z;
  int wb = blockIdx.y;              // 0..16
  int nb = blockIdx.x;              // 0..31
  int w0 = wb * 25;
  int qb = w0 * 10 - 2;
  int n0 = nb * 128;
  int nwin = SP - w0; if (nwin > 25) nwin = 25;

  __shared__ __align__(16) union SM {
    struct { char A[2][32768]; char Bm[2][16384]; } st;
    float pm[9216];                                 // 128 pairs x stride 72 (f32)
  } sm;

  const char* qpc = (const char*)(qp + (size_t)b * S * 256);
  const char* kpc = (const char*)(kp + (size_t)b * S * 256);

  int tid  = threadIdx.x;
  int lane = tid & 63, wid = tid >> 6;
  int wr = wid >> 1, wc = wid & 1;       // 4x2 wave grid, each 64x64
  int lrow = lane & 15, kseg = lane >> 4;

  f32x4 zero4 = {0.f, 0.f, 0.f, 0.f};
  f32x4 acc[4][4];
#pragma unroll
  for (int i = 0; i < 4; i++)
#pragma unroll
    for (int j = 0; j < 4; j++) acc[i][j] = zero4;

  auto stage = [&](int t, int buf) {
#pragma unroll
    for (int i = 0; i < 4; ++i) {
      int inst = wid * 4 + i;
      int sg   = inst * 64 + lane;
      int row  = sg >> 3, c16 = sg & 7;
      int q = qb + row; q = (q < 0) ? 0 : ((q > S - 1) ? (S - 1) : q);
      gload16(qpc + ((size_t)q << 9) + (t << 7) + ((c16 ^ (row & 7)) << 4),
              sm.st.A[buf] + inst * 1024);
    }
#pragma unroll
    for (int i = 0; i < 2; ++i) {
      int inst = wid * 2 + i;
      int sg   = inst * 64 + lane;
      int row  = sg >> 3, c16 = sg & 7;
      gload16(kpc + ((size_t)(n0 + row) << 9) + (t << 7) + ((c16 ^ (row & 7)) << 4),
              sm.st.Bm[buf] + inst * 1024);
    }
  };

  stage(0, 0);
  __syncthreads();
#pragma unroll
  for (int t = 0; t < 4; ++t) {
    int cur = t & 1;
    if (t < 3) stage(t + 1, cur ^ 1);
    const char* Asm = sm.st.A[cur];
    const char* Bsm = sm.st.Bm[cur];
#pragma unroll
    for (int kk = 0; kk < 2; ++kk) {
      bf16x8 af[4], bfr[4];
#pragma unroll
      for (int mi = 0; mi < 4; ++mi) {
        int R = wr * 64 + mi * 16 + lrow;
        int c16 = (kk * 4 + kseg) ^ (R & 7);
        af[mi] = *reinterpret_cast<const bf16x8*>(Asm + R * 128 + c16 * 16);
      }
#pragma unroll
      for (int cf = 0; cf < 4; ++cf) {
        int nl = wc * 64 + cf * 16 + lrow;
        int c16 = (kk * 4 + kseg) ^ (nl & 7);
        bfr[cf] = *reinterpret_cast<const bf16x8*>(Bsm + nl * 128 + c16 * 16);
      }
#pragma unroll
      for (int mi = 0; mi < 4; ++mi)
#pragma unroll
        for (int cf = 0; cf < 4; ++cf)
          acc[mi][cf] = mfma16(af[mi], bfr[cf], acc[mi][cf]);
    }
    __syncthreads();
  }

  // ---- pooling: in-register pair-max -> LDS [128 pairs][72] f32 -> 5-way window max
  int h = kseg;
#pragma unroll
  for (int c = 0; c < 2; ++c) {
    __syncthreads();
    if (wc == c) {
#pragma unroll
      for (int mi = 0; mi < 4; ++mi) {
        int p = wr * 32 + mi * 8 + h * 2;
#pragma unroll
        for (int cf = 0; cf < 4; ++cf) {
          int col = cf * 16 + lrow;
          sm.pm[p * 72 + col]       = fmaxf(acc[mi][cf][0], acc[mi][cf][1]);
          sm.pm[(p + 1) * 72 + col] = fmaxf(acc[mi][cf][2], acc[mi][cf][3]);
        }
      }
    }
    __syncthreads();
    for (int s = tid; s < 1600; s += 512) {
      int j = s >> 6, col = s & 63;
      if (j < nwin) {
        float m = -3.4e38f;
#pragma unroll
        for (int i = 0; i < 5; ++i) {
          int p  = 5 * j + i;
          int q0 = qb + 2 * p;
          if (q0 >= 0 && q0 < S) m = fmaxf(m, sm.pm[p * 72 + col]);
        }
        pooled[((size_t)b * SP + w0 + j) * 4096 + n0 + c * 64 + col] = m * 0.0625f;
      }
    }
  }
}

// ---------- K3: row softmax (4096 cols), fp32 in, bf16 out ----------
__global__ __launch_bounds__(256) void softmax_kernel(
    const float* __restrict__ pooled, unsigned short* __restrict__ attn)
{
  int row = blockIdx.x;
  const float* p = pooled + (size_t)row * 4096;
  unsigned short* a = attn + (size_t)row * 4096;
  int tid = threadIdx.x;
  int lane = tid & 63, wid = tid >> 6;

  f4 v[4];
  float mx = -3.4e38f;
#pragma unroll
  for (int i = 0; i < 4; i++) {
    v[i] = *reinterpret_cast<const f4*>(&p[i * 1024 + tid * 4]);
    mx = fmaxf(mx, fmaxf(fmaxf(v[i][0], v[i][1]), fmaxf(v[i][2], v[i][3])));
  }
#pragma unroll
  for (int off = 32; off > 0; off >>= 1) mx = fmaxf(mx, __shfl_xor(mx, off, 64));
  __shared__ float redm[4];
  __shared__ float reds[4];
  if (lane == 0) redm[wid] = mx;
  __syncthreads();
  mx = fmaxf(fmaxf(redm[0], redm[1]), fmaxf(redm[2], redm[3]));

  float e[16];
  float sum = 0.f;
#pragma unroll
  for (int i = 0; i < 4; i++)
#pragma unroll
    for (int j = 0; j < 4; j++) {
      float t = __expf(v[i][j] - mx);
      e[i * 4 + j] = t;
      sum += t;
    }
#pragma unroll
  for (int off = 32; off > 0; off >>= 1) sum += __shfl_xor(sum, off, 64);
  if (lane == 0) reds[wid] = sum;
  __syncthreads();
  sum = reds[0] + reds[1] + reds[2] + reds[3];
  float inv = 1.f / sum;
#pragma unroll
  for (int i = 0; i < 4; i++) {
    u16x4 o;
#pragma unroll
    for (int j = 0; j < 4; j++) o[j] = f2bf(e[i * 4 + j] * inv);
    *reinterpret_cast<u16x4*>(&a[i * 1024 + tid * 4]) = o;
  }
}

// ---------- K4a: transpose vp [b][k][d] -> vpT [b][d][k] ----------
__global__ __launch_bounds__(256) void vpt_kernel(
    const unsigned short* __restrict__ vp, unsigned short* __restrict__ vpT)
{
  int b  = blockIdx.y;
  int kt = blockIdx.x >> 2;
  int dt = blockIdx.x & 3;
  int k0 = kt * 64, d0 = dt * 64;

  __shared__ unsigned short t[64][66];
  const unsigned short* src = vp + (size_t)b * S * 256;
  unsigned short* dst = vpT + (size_t)b * 256 * S;

  int tid = threadIdx.x;
  for (int s = tid; s < 512; s += 256) {
    int r = s >> 3, seg = s & 7;
    u16x8 v = *reinterpret_cast<const u16x8*>(&src[(size_t)(k0 + r) * 256 + d0 + seg * 8]);
#pragma unroll
    for (int j = 0; j < 4; j++) {
      unsigned short* pp = &t[r][seg * 8 + j * 2];
      pp[0] = v[j * 2]; pp[1] = v[j * 2 + 1];
    }
  }
  __syncthreads();
  int d  = tid >> 2;
  int kb = (tid & 3) * 16;
  u16x8 o0, o1;
#pragma unroll
  for (int j = 0; j < 8; j++) o0[j] = t[kb + j][d];
#pragma unroll
  for (int j = 0; j < 8; j++) o1[j] = t[kb + 8 + j][d];
  *reinterpret_cast<u16x8*>(&dst[(size_t)(d0 + d) * S + k0 + kb])     = o0;
  *reinterpret_cast<u16x8*>(&dst[(size_t)(d0 + d) * S + k0 + kb + 8]) = o1;
}

// ---------- K4: PV GEMM, split-K=16, stage-ahead dbuf, partials to ws ----------
__global__ __launch_bounds__(256) void pv_kernel(
    const unsigned short* __restrict__ attn, const unsigned short* __restrict__ vpT,
    float* __restrict__ part)
{
  int bx = blockIdx.x;
  int b  = bx >> 2, mt = bx & 3;
  int m0 = mt * 128;
  int n0 = blockIdx.y * 128;
  int kz = blockIdx.z;
  int k0b = kz * 512;                  // byte offset of k-chunk start (256 k * 2B)

  const char* Ac = (const char*)(attn + (size_t)b * SP * 4096);
  const char* Bc = (const char*)(vpT  + (size_t)b * 256 * 4096);
  float* Pz = part + (size_t)kz * PSLICE;

  __shared__ __align__(16) struct { char A[2][16384]; char Bm[2][16384]; } sm;

  int tid  = threadIdx.x;
  int lane = tid & 63, wid = tid >> 6;
  int wr = wid >> 1, wc = wid & 1;      // 2x2 waves, 64x64
  int lrow = lane & 15, kseg = lane >> 4;

  f32x4 zero4 = {0.f, 0.f, 0.f, 0.f};
  f32x4 acc[4][4];
#pragma unroll
  for (int i = 0; i < 4; i++)
#pragma unroll
    for (int j = 0; j < 4; j++) acc[i][j] = zero4;

  auto stage = [&](int t, int buf) {
#pragma unroll
    for (int i = 0; i < 4; ++i) {                   // A: 128 rows x 64k (attn, row stride 8192B)
      int inst = wid * 4 + i;
      int sg   = inst * 64 + lane;
      int row  = sg >> 3, c16 = sg & 7;
      int m = m0 + row; m = (m > SP - 1) ? (SP - 1) : m;
      gload16(Ac + (size_t)m * 8192 + k0b + (t << 7) + ((c16 ^ (row & 7)) << 4),
              sm.A[buf] + inst * 1024);
    }
#pragma unroll
    for (int i = 0; i < 4; ++i) {                   // B: 128 rows x 64k (vpT, row stride 8192B)
      int inst = wid * 4 + i;
      int sg   = inst * 64 + lane;
      int row  = sg >> 3, c16 = sg & 7;
      gload16(Bc + (size_t)(n0 + row) * 8192 + k0b + (t << 7) + ((c16 ^ (row & 7)) << 4),
              sm.Bm[buf] + inst * 1024);
    }
  };

  stage(0, 0);
  __syncthreads();
#pragma unroll
  for (int t = 0; t < 4; ++t) {
    int cur = t & 1;
    if (t < 3) stage(t + 1, cur ^ 1);
    const char* Asm = sm.A[cur];
    const char* Bsm = sm.Bm[cur];
#pragma unroll
    for (int kk = 0; kk < 2; ++kk) {
      bf16x8 af[4], bfr[4];
#pragma unroll
      for (int mi = 0; mi < 4; ++mi) {
        int R = wr * 64 + mi * 16 + lrow;
        int c16 = (kk * 4 + kseg) ^ (R & 7);
        af[mi] = *reinterpret_cast<const bf16x8*>(Asm + R * 128 + c16 * 16);
      }
#pragma unroll
      for (int cf = 0; cf < 4; ++cf) {
        int nl = wc * 64 + cf * 16 + lrow;
        int c16 = (kk * 4 + kseg) ^ (nl & 7);
        bfr[cf] = *reinterpret_cast<const bf16x8*>(Bsm + nl * 128 + c16 * 16);
      }
#pragma unroll
      for (int mi = 0; mi < 4; ++mi)
#pragma unroll
        for (int cf = 0; cf < 4; ++cf)
          acc[mi][cf] = mfma16(af[mi], bfr[cf], acc[mi][cf]);
    }
    __syncthreads();
  }

  int r4 = kseg * 4;
#pragma unroll
  for (int mi = 0; mi < 4; mi++)
#pragma unroll
    for (int cf = 0; cf < 4; cf++) {
      int n = n0 + wc * 64 + cf * 16 + lrow;
#pragma unroll
      for (int r = 0; r < 4; r++) {
        int m = m0 + wr * 64 + mi * 16 + r4 + r;
        if (m < SP) Pz[((size_t)b * SP + m) * 256 + n] = acc[mi][cf][r];
      }
    }
}

// ---------- K4b: sum 16 partials -> ctx bf16 ----------
__global__ __launch_bounds__(256) void reduce_kernel(
    const float* __restrict__ part, unsigned short* __restrict__ ctxb)
{
  size_t i = (size_t)blockIdx.x * 256 + threadIdx.x;   // PSLICE elements
  float s = 0.f;
#pragma unroll
  for (int z = 0; z < KZ; ++z) s += part[z * PSLICE + i];
  ctxb[i] = f2bf(s);
}

// ---------- K5: out = ctx @ wo + bo (fp32 out), stage-ahead dbuf ----------
__global__ __launch_bounds__(512) void out_kernel(
    const unsigned short* __restrict__ ctxb, const unsigned short* __restrict__ woT,
    const float* __restrict__ bo, float* __restrict__ out)
{
  int m0 = blockIdx.x * 256;           // over MO=1640
  int n0 = blockIdx.y * 128;

  __shared__ __align__(16) struct { char A[2][32768]; char Bm[2][16384]; } sm;

  const char* Xc = (const char*)ctxb;
  const char* Wc = (const char*)woT;

  int tid  = threadIdx.x;
  int lane = tid & 63, wid = tid >> 6;
  int wr = wid >> 1, wc = wid & 1;
  int lrow = lane & 15, kseg = lane >> 4;

  f32x4 zero4 = {0.f, 0.f, 0.f, 0.f};
  f32x4 acc[4][4];
#pragma unroll
  for (int i = 0; i < 4; i++)
#pragma unroll
    for (int j = 0; j < 4; j++) acc[i][j] = zero4;

  auto stage = [&](int t, int buf) {
#pragma unroll
    for (int i = 0; i < 4; ++i) {
      int inst = wid * 4 + i;
      int sg   = inst * 64 + lane;
      int row  = sg >> 3, c16 = sg & 7;
      int m = m0 + row; m = (m > MO - 1) ? (MO - 1) : m;
      gload16(Xc + ((size_t)m << 9) + (t << 7) + ((c16 ^ (row & 7)) << 4),
              sm.A[buf] + inst * 1024);
    }
#pragma unroll
    for (int i = 0; i < 2; ++i) {
      int inst = wid * 2 + i;
      int sg   = inst * 64 + lane;
      int row  = sg >> 3, c16 = sg & 7;
      gload16(Wc + ((size_t)(n0 + row) << 9) + (t << 7) + ((c16 ^ (row & 7)) << 4),
              sm.Bm[buf] + inst * 1024);
    }
  };

  stage(0, 0);
  __syncthreads();
#pragma unroll
  for (int t = 0; t < 4; ++t) {
    int cur = t & 1;
    if (t < 3) stage(t + 1, cur ^ 1);
    const char* Asm = sm.A[cur];
    const char* Bsm = sm.Bm[cur];
#pragma unroll
    for (int kk = 0; kk < 2; ++kk) {
      bf16x8 af[4], bfr[4];
#pragma unroll
      for (int mi = 0; mi < 4; ++mi) {
        int R = wr * 64 + mi * 16 + lrow;
        int c16 = (kk * 4 + kseg) ^ (R & 7);
        af[mi] = *reinterpret_cast<const bf16x8*>(Asm + R * 128 + c16 * 16);
      }
#pragma unroll
      for (int cf = 0; cf < 4; ++cf) {
        int nl = wc * 64 + cf * 16 + lrow;
        int c16 = (kk * 4 + kseg) ^ (nl & 7);
        bfr[cf] = *reinterpret_cast<const bf16x8*>(Bsm + nl * 128 + c16 * 16);
      }
#pragma unroll
      for (int mi = 0; mi < 4; ++mi)
#pragma unroll
        for (int cf = 0; cf < 4; ++cf)
          acc[mi][cf] = mfma16(af[mi], bfr[cf], acc[mi][cf]);
    }
    __syncthreads();
  }

  int r4 = kseg * 4;
#pragma unroll
  for (int mi = 0; mi < 4; mi++)
#pragma unroll
    for (int cf = 0; cf < 4; cf++) {
      int n = n0 + wc * 64 + cf * 16 + lrow;
      float bv_ = bo[n];
#pragma unroll
      for (int r = 0; r < 4; r++) {
        int m = m0 + wr * 64 + mi * 16 + r4 + r;
        if (m < MO) out[(size_t)m * 256 + n] = acc[mi][cf][r] + bv_;
      }
    }
}

// ---------- launch ----------
extern "C" void kernel_launch(void* const* d_in, const int* in_sizes, int n_in,
                              void* d_out, int out_size, void* d_ws, size_t ws_size,
                              hipStream_t stream)
{
  const float* v  = (const float*)d_in[0];
  const float* k  = (const float*)d_in[1];
  const float* q  = (const float*)d_in[2];
  const float* wq = (const float*)d_in[3];
  const float* bq = (const float*)d_in[4];
  const float* wk = (const float*)d_in[5];
  const float* bk = (const float*)d_in[6];
  const float* wv = (const float*)d_in[7];
  const float* bv = (const float*)d_in[8];
  const float* wo = (const float*)d_in[9];
  const float* bo = (const float*)d_in[10];
  float* out = (float*)d_out;

  char* ws = (char*)d_ws;
  size_t off = 0;
  auto alloc = [&](size_t bytes) -> void* {
    void* p = ws + off;
    off += (bytes + 255) & ~(size_t)255;
    return p;
  };
  unsigned short* qp   = (unsigned short*)alloc((size_t)B * S * D * 2);     // 8 MB
  unsigned short* kp   = (unsigned short*)alloc((size_t)B * S * D * 2);     // 8 MB
  unsigned short* vp   = (unsigned short*)alloc((size_t)B * S * D * 2);     // 8 MB
  unsigned short* vpT  = (unsigned short*)alloc((size_t)B * S * D * 2);     // 8 MB
  unsigned short* wt   = (unsigned short*)alloc((size_t)4 * 256 * 256 * 2); // 0.5 MB
  unsigned short* ctxb = (unsigned short*)alloc(PSLICE * 2);                // 0.84 MB
  // shared region (disjoint lifetimes): qx/kx/vx [cvt->proj], pooled [scores->softmax],
  // part [pv->reduce]; max size = pooled = 26.9 MB >= 3*8.4 (qx..) and 16*1.68 (part)
  char* shared_region  = (char*)alloc((size_t)B * SP * 4096 * 4);
  unsigned short* attn = (unsigned short*)alloc((size_t)B * SP * 4096 * 2); // 13.4 MB

  unsigned short* qx = (unsigned short*)shared_region;
  unsigned short* kx = qx + (size_t)B * S * D;
  unsigned short* vx = kx + (size_t)B * S * D;
  float* pooled = (float*)shared_region;
  float* part   = (float*)shared_region;

  wt_trans_kernel<<<1024, 256, 0, stream>>>(wq, wk, wv, wo, wt);
  cvt_kernel<<<dim3(2048, 3), 256, 0, stream>>>(q, k, v, qx, kx, vx);
  proj_kernel<<<dim3(64, 2, 3), 512, 0, stream>>>(qx, kx, vx, wt, bq, bk, bv, qp, kp, vp);
  scores_pool_kernel<<<dim3(32, 17, 4), 512, 0, stream>>>(qp, kp, pooled);
  softmax_kernel<<<B * SP, 256, 0, stream>>>(pooled, attn);
  vpt_kernel<<<dim3(256, 4), 256, 0, stream>>>(vp, vpT);
  pv_kernel<<<dim3(16, 2, KZ), 256, 0, stream>>>(attn, vpT, part);
  reduce_kernel<<<(int)(PSLICE / 256), 256, 0, stream>>>(part, ctxb);
  out_kernel<<<dim3(7, 2), 512, 0, stream>>>(ctxb, wt + 3 * 65536, bo, out);
}